// Round 12
// baseline (321.046 us; speedup 1.0000x reference)
//
#include <hip/hip_runtime.h>

#define N    8192
#define DT   768
#define DO   512
#define BM   128
#define BN   128
#define TI   (N / BM)   // 64
#define TJ   (N / BN)   // 64
#define NTILE (TI * (TI + 1) / 2)   // 2080 upper-triangle tiles (2080 % 8 == 0)
#define NSLOT (2 * TJ)              // 128 partial slots per row
#define PL    ((size_t)NSLOT * N)   // one SoA plane: 128*8192 floats = 4 MB
#define NKT   (DT / 32)             // 24 teacher K-chunks
#define NKO   (DO / 32)             // 16 student K-chunks
#define NSTEP (NKT + NKO)           // 40

typedef __attribute__((ext_vector_type(8))) short   short8;   // 8 bf16 = 4 VGPRs
typedef __attribute__((ext_vector_type(4))) float   floatx4;

struct alignas(8) us4 { unsigned short x[4]; };

// round-to-nearest-even fp32 -> bf16
__device__ inline unsigned short f2bf(float x) {
    union { float f; unsigned int u; } v; v.f = x;
    unsigned int r = v.u + 0x7fffu + ((v.u >> 16) & 1u);
    return (unsigned short)(r >> 16);
}
__device__ inline float bf2f(unsigned short u) {
    union { unsigned int u; float f; } v; v.u = ((unsigned int)u) << 16;
    return v.f;
}

// async global->LDS, 16B per lane (global_load_lds_dwordx4)
__device__ inline void gl2lds16(const unsigned short* g, unsigned short* l) {
    __builtin_amdgcn_global_load_lds(
        (const __attribute__((address_space(1))) unsigned int*)(const void*)g,
        (__attribute__((address_space(3))) unsigned int*)(void*)l,
        16, 0, 0);
}

// ---- K-major PACKED staging layout (R11, proven) ----------------------------
// packed[(p*NKC + kc)*4096 + (r*4 + cs)*8 + e]; cs = chunk ^ ((r>>1)&3) bakes
// the bank-conflict swizzle so each (p,kc) 8KB block streams sequentially.
template <int NKC>
__device__ inline void stage_packed(const unsigned short* __restrict__ P,
                                    unsigned short* sA, unsigned short* sB,
                                    int pi, int pj, int s, int t) {
    const unsigned short* bi = P + ((size_t)(pi * NKC + s) << 12);
    const unsigned short* bj = P + ((size_t)(pj * NKC + s) << 12);
    #pragma unroll
    for (int h = 0; h < 2; ++h) {
        const int idx = t + h * 256;        // 0..511; fully sequential stream
        gl2lds16(bi + idx * 8, &sA[idx * 8]);
        gl2lds16(bj + idx * 8, &sB[idx * 8]);
    }
}

// bid -> (ti, tj): chunked XCD swizzle + SUPER-BLOCK enumeration (R8/R10).
__device__ inline void tile_coords(int bid, int& ti, int& tj) {
    int swb = (bid & 7) * (NTILE / 8) + (bid >> 3);   // contiguous per XCD
    int sti = 0, stj = 0;
    for (;;) {
        const int sz = (sti == stj) ? 36 : 64;
        if (swb < sz) break;
        swb -= sz;
        if (++stj == 8) { ++sti; stj = sti; }
    }
    int i, j;
    if (sti == stj) {
        i = 0;
        while (swb >= 8 - i) { swb -= 8 - i; ++i; }
        j = i + swb;
    } else {
        i = swb >> 3;
        j = swb & 7;
    }
    ti = sti * 8 + i;
    tj = stj * 8 + j;
}

// ---------------- row-normalize fp32 -> bf16 INTO PACKED LAYOUT ---------------
__global__ void norm_kernel(const float* __restrict__ Tg,
                            const float* __restrict__ Mo,
                            unsigned short* __restrict__ Pt,
                            unsigned short* __restrict__ Po,
                            float* __restrict__ zero_me) {
    if (blockIdx.x == 0 && threadIdx.x == 0) zero_me[0] = 0.0f;
    int bid = blockIdx.x;
    const float* X; unsigned short* Pk; int D, NKC;
    if (bid < N / 4) { X = Tg; Pk = Pt; D = DT; NKC = NKT; }
    else             { bid -= N / 4; X = Mo; Pk = Po; D = DO; NKC = NKO; }
    const int row  = bid * 4 + (threadIdx.x >> 6);
    const int lane = threadIdx.x & 63;
    const int nch  = D >> 8;                       // 3 (DT) or 2 (DO)
    const int r    = row & 127;
    const int p    = row >> 7;
    const int key  = (r >> 1) & 3;
    const float* xr = X + (size_t)row * D;
    floatx4 vc[3];
    float ss = 0.0f;
    #pragma unroll
    for (int h = 0; h < 3; ++h) {
        if (h < nch) {
            vc[h] = *(const floatx4*)(xr + lane * 4 + h * 256);
            ss += vc[h][0] * vc[h][0] + vc[h][1] * vc[h][1]
                + vc[h][2] * vc[h][2] + vc[h][3] * vc[h][3];
        }
    }
    #pragma unroll
    for (int m = 32; m >= 1; m >>= 1) ss += __shfl_xor(ss, m);
    const float scale = 1.0f / fmaxf(sqrtf(ss), 1e-8f);
    #pragma unroll
    for (int h = 0; h < 3; ++h) {
        if (h < nch) {
            us4 o;
            #pragma unroll
            for (int j = 0; j < 4; ++j) o.x[j] = f2bf(vc[h][j] * scale);
            const int k0  = lane * 4 + h * 256;
            const int kc  = k0 >> 5;
            const int ch  = (k0 >> 3) & 3;
            const int cs  = ch ^ key;
            const int pos = (k0 >> 2) & 1;
            const size_t a = ((size_t)(p * NKC + kc) << 12)
                           + (size_t)(r * 4 + cs) * 8 + pos * 4;
            *(us4*)(Pk + a) = o;
        }
    }
}

// ---------------- fused dual-GEMM + softmax-stat tile kernel (R12) ------------
// R11 structure + ring-2 ONE-BARRIER pipelined K-loop:
//   iter s: vmcnt(0) [loads issued a FULL ITERATION earlier -> ~free] ;
//           s_barrier ; stage(s+1) into buf[(s+1)&1] ; compute buf[s&1].
// Write-safety (ring-2): buf[(s+1)&1] was last read during compute(s-1),
// which every wave finished before crossing this barrier.
// Unified step index 0..39 (24 teacher + 16 student); teacher iter 23 stages
// the student's chunk 0; teacher epilogue (~1500 cy VALU) hides its latency.
// W = e3: idx 0..31 in LDS sWl (16 KB), idx 32..63 packed in 16 VGPRs ->
// LDS = 2x8K A + 2x8K B + 16K sWl = 48 KB -> 3 blocks/CU; VGPR ~100 (no spill).
__launch_bounds__(256, 3)
__global__ void fused_kernel(const unsigned short* __restrict__ Pt,
                             const unsigned short* __restrict__ Po,
                             float* __restrict__ partials) {
    __shared__ unsigned short sA[2][BM * 32];  // 2 x 8 KB
    __shared__ unsigned short sB[2][BN * 32];  // 2 x 8 KB
    __shared__ unsigned short sWl[32 * 256];   // 16 KB: W idx 0..31 [idx][thread]

    const int t    = threadIdx.x;
    const int lane = t & 63;
    const int w    = t >> 6;
    const int wm   = w >> 1, wn = w & 1;
    const int lr   = lane & 15, lg = lane >> 4;
    const int lgx  = lg ^ ((lr >> 1) & 3);     // swizzled read chunk index

    int ti, tj; tile_coords(blockIdx.x, ti, tj);
    const bool offdiag = (ti != tj);
    const int i0 = ti * BM, j0 = tj * BN;

    unsigned int w3p[16];                      // W idx 32..63 (bf16 pairs)
    floatx4 acc[4][4];
    #pragma unroll
    for (int a = 0; a < 4; ++a)
        #pragma unroll
        for (int b = 0; b < 4; ++b)
            acc[a][b] = (floatx4){0.0f, 0.0f, 0.0f, 0.0f};

    // stage unified step u: u<NKT -> teacher chunk u ; else student chunk u-NKT
    auto stage_any = [&](int u) {
        unsigned short* a = sA[u & 1];
        unsigned short* b = sB[u & 1];
        if (u < NKT) stage_packed<NKT>(Pt, a, b, ti, tj, u, t);
        else         stage_packed<NKO>(Po, a, b, ti, tj, u - NKT, t);
    };

    // fragment loads + 16 MFMA for one 32-wide K-step
    auto mfma_step = [&](const unsigned short* sAb, const unsigned short* sBb) {
        short8 af[4], bf[4];
        #pragma unroll
        for (int mi = 0; mi < 4; ++mi)
            af[mi] = *(const short8*)&sAb[(wm * 64 + mi * 16 + lr) * 32 + (lgx << 3)];
        #pragma unroll
        for (int ni = 0; ni < 4; ++ni)
            bf[ni] = *(const short8*)&sBb[(wn * 64 + ni * 16 + lr) * 32 + (lgx << 3)];
        #pragma unroll
        for (int mi = 0; mi < 4; ++mi)
            #pragma unroll
            for (int ni = 0; ni < 4; ++ni)
                acc[mi][ni] = __builtin_amdgcn_mfma_f32_16x16x32_bf16(
                    af[mi], bf[ni], acc[mi][ni], 0, 0, 0);
    };

    // ---- prologue + teacher K-loop (steps 0..23, pipelined, 1 barrier/step) --
    stage_any(0);
    for (int s = 0; s < NKT; ++s) {
        asm volatile("s_waitcnt vmcnt(0)" ::: "memory");   // stage(s): ~free
        __builtin_amdgcn_s_barrier();
        asm volatile("" ::: "memory");
        stage_any(s + 1);                                  // s+1 == 24 -> student 0
        mfma_step(sA[s & 1], sB[s & 1]);
        asm volatile("" ::: "memory");
    }

    // ---- teacher epilogue: Zt, V, Sum(e3*a) (both orientations); W parked
    //      idx<32 -> sWl, idx>=32 -> w3p regs. Student chunk 0 lands underneath.
    // C/D layout: col = lane&15, row = (lane>>4)*4 + reg
    {
        float czt[4], cvv[4], cua[4];
        #pragma unroll
        for (int ni = 0; ni < 4; ++ni) { czt[ni] = 0.0f; cvv[ni] = 0.0f; cua[ni] = 0.0f; }
        #pragma unroll
        for (int mi = 0; mi < 4; ++mi) {
            #pragma unroll
            for (int r = 0; r < 4; ++r) {
                const int row = wm * 64 + mi * 16 + lg * 4 + r;
                const int gi  = i0 + row;
                float zt = 0.0f, vv = 0.0f, ua = 0.0f;
                #pragma unroll
                for (int ni = 0; ni < 4; ++ni) {
                    const int gj = j0 + wn * 64 + ni * 16 + lr;
                    const float a = acc[mi][ni][r];
                    float ea = __expf(a - 1.0f);
                    if (gi == gj) ea = 0.0f;               // diagonal -> prob 0
                    const float e3 = ea * ea * ea;
                    zt += ea; vv += e3; ua += e3 * a;
                    czt[ni] += ea; cvv[ni] += e3; cua[ni] += e3 * a;
                    const int idx = mi * 16 + ni * 4 + r;  // compile-time constant
                    if (idx < 32) {
                        sWl[idx * 256 + t] = f2bf(e3);
                    } else {
                        const int q = (idx - 32) >> 1;
                        if (idx & 1) w3p[q] |= ((unsigned int)f2bf(e3)) << 16;
                        else         w3p[q]  = (unsigned int)f2bf(e3);
                    }
                }
                #pragma unroll
                for (int m = 8; m >= 1; m >>= 1) {
                    zt += __shfl_xor(zt, m);
                    vv += __shfl_xor(vv, m);
                    ua += __shfl_xor(ua, m);
                }
                if (lr == 0) {
                    const size_t base = (size_t)(tj * 2 + wn) * N + gi;
                    partials[0 * PL + base] = zt;
                    partials[1 * PL + base] = vv;
                    partials[2 * PL + base] = ua;
                }
            }
        }
        if (offdiag) {
            #pragma unroll
            for (int ni = 0; ni < 4; ++ni) {
                #pragma unroll
                for (int m = 16; m <= 32; m <<= 1) {
                    czt[ni] += __shfl_xor(czt[ni], m);
                    cvv[ni] += __shfl_xor(cvv[ni], m);
                    cua[ni] += __shfl_xor(cua[ni], m);
                }
            }
            if (lg == 0) {
                #pragma unroll
                for (int ni = 0; ni < 4; ++ni) {
                    const int gj = j0 + wn * 64 + ni * 16 + lr;   // contiguous in lr
                    const size_t base = (size_t)(ti * 2 + wm) * N + gj;
                    partials[0 * PL + base] = czt[ni];
                    partials[1 * PL + base] = cvv[ni];
                    partials[2 * PL + base] = cua[ni];
                }
            }
        }
    }

    // ---- student K-loop (steps 24..39, same cadence) ----
    #pragma unroll
    for (int a = 0; a < 4; ++a)
        #pragma unroll
        for (int b = 0; b < 4; ++b)
            acc[a][b] = (floatx4){0.0f, 0.0f, 0.0f, 0.0f};

    for (int s = NKT; s < NSTEP; ++s) {
        // vmcnt(0) also drains the one-time epilogue partials stores at s==24.
        asm volatile("s_waitcnt vmcnt(0)" ::: "memory");
        __builtin_amdgcn_s_barrier();
        asm volatile("" ::: "memory");
        if (s + 1 < NSTEP) stage_any(s + 1);
        mfma_step(sA[s & 1], sB[s & 1]);
        asm volatile("" ::: "memory");
    }

    // ---- final epilogue: Zo, Sum(W*b) (both orientations) ----
    {
        float czo[4], cwb[4];
        #pragma unroll
        for (int ni = 0; ni < 4; ++ni) { czo[ni] = 0.0f; cwb[ni] = 0.0f; }
        #pragma unroll
        for (int mi = 0; mi < 4; ++mi) {
            #pragma unroll
            for (int r = 0; r < 4; ++r) {
                const int row = wm * 64 + mi * 16 + lg * 4 + r;
                const int gi  = i0 + row;
                float zo = 0.0f, wb = 0.0f;
                #pragma unroll
                for (int ni = 0; ni < 4; ++ni) {
                    const int gj = j0 + wn * 64 + ni * 16 + lr;
                    const float b = acc[mi][ni][r];
                    float eb = __expf(b - 1.0f);
                    if (gi == gj) eb = 0.0f;
                    const int idx = mi * 16 + ni * 4 + r;  // compile-time constant
                    float wgt;
                    if (idx < 32) {
                        wgt = bf2f(sWl[idx * 256 + t]);
                    } else {
                        const unsigned int pw = w3p[(idx - 32) >> 1];
                        wgt = bf2f((unsigned short)((idx & 1) ? (pw >> 16)
                                                              : (pw & 0xffffu)));
                    }
                    zo += eb; wb += wgt * b;   // diag: W==0 -> no contribution
                    czo[ni] += eb; cwb[ni] += wgt * b;
                }
                #pragma unroll
                for (int m = 8; m >= 1; m >>= 1) {
                    zo += __shfl_xor(zo, m);
                    wb += __shfl_xor(wb, m);
                }
                if (lr == 0) {
                    const size_t base = (size_t)(tj * 2 + wn) * N + gi;
                    partials[3 * PL + base] = zo;
                    partials[4 * PL + base] = wb;
                }
            }
        }
        if (offdiag) {
            #pragma unroll
            for (int ni = 0; ni < 4; ++ni) {
                #pragma unroll
                for (int m = 16; m <= 32; m <<= 1) {
                    czo[ni] += __shfl_xor(czo[ni], m);
                    cwb[ni] += __shfl_xor(cwb[ni], m);
                }
            }
            if (lg == 0) {
                #pragma unroll
                for (int ni = 0; ni < 4; ++ni) {
                    const int gj = j0 + wn * 64 + ni * 16 + lr;   // contiguous in lr
                    const size_t base = (size_t)(ti * 2 + wm) * N + gj;
                    partials[3 * PL + base] = czo[ni];
                    partials[4 * PL + base] = cwb[ni];
                }
            }
        }
    }
}

// ---------------- final per-row combine + scalar reduce ----------------
__global__ void reduce_kernel(const float* __restrict__ partials,
                              float* __restrict__ out) {
    __shared__ float sh[5][256];
    const int t    = threadIdx.x;
    const int lane = t & 63;
    const int g    = t >> 6;
    const int i    = blockIdx.x * 64 + lane;      // row (coalesced across lanes)
    float s[5] = {0.0f, 0.0f, 0.0f, 0.0f, 0.0f};
    for (int jb = g * (NSLOT / 4); jb < (g + 1) * (NSLOT / 4); ++jb) {
        const size_t base = (size_t)jb * N + i;
        #pragma unroll
        for (int p = 0; p < 5; ++p) s[p] += partials[p * PL + base];
    }
    #pragma unroll
    for (int p = 0; p < 5; ++p) sh[p][t] = s[p];
    __syncthreads();
    if (g == 0) {
        float v[5];
        #pragma unroll
        for (int p = 0; p < 5; ++p)
            v[p] = sh[p][lane] + sh[p][64 + lane] + sh[p][128 + lane] + sh[p][192 + lane];
        // loss_i = (UA - WB + V*log(Zo/Zt)) / Zt^3
        float li = (v[2] - v[4] + v[1] * __logf(v[3] / v[0])) / (v[0] * v[0] * v[0]);
        #pragma unroll
        for (int m = 32; m >= 1; m >>= 1) li += __shfl_xor(li, m);
        if (lane == 0)
            atomicAdd(out, li * (1.0f / ((float)N * (float)N)));   // WEIGHT=1
    }
}

extern "C" void kernel_launch(void* const* d_in, const int* in_sizes, int n_in,
                              void* d_out, int out_size, void* d_ws, size_t ws_size,
                              hipStream_t stream) {
    (void)in_sizes; (void)n_in; (void)out_size; (void)ws_size;
    const float* mo = (const float*)d_in[0];   // model_output [8192,512] fp32
    const float* tg = (const float*)d_in[1];   // targets      [8192,768] fp32
    float* out = (float*)d_out;

    char* ws = (char*)d_ws;
    unsigned short* Pt = (unsigned short*)ws;                          // 12.58 MB packed
    unsigned short* Po = (unsigned short*)(ws + (size_t)N * DT * 2);   //  8.39 MB packed
    float* partials    = (float*)(ws + (size_t)N * DT * 2 + (size_t)N * DO * 2);
    // partials: 5 planes * 128 * 8192 * 4 B = 20.97 MB; total ws use ~41.9 MB

    norm_kernel<<<2 * (N / 4), 256, 0, stream>>>(tg, mo, Pt, Po, out);  // also zeroes out
    fused_kernel<<<NTILE, 256, 0, stream>>>(Pt, Po, partials);
    reduce_kernel<<<N / 64, 256, 0, stream>>>(partials, out);
}